// Round 1
// baseline (304.410 us; speedup 1.0000x reference)
//
#include <hip/hip_runtime.h>

#define N_NODES 50000
#define N_EDGES 800000
#define IN_DIM 128
#define OUT_DIM 64

// ---------------------------------------------------------------------------
// Kernel 1: h = x @ w   (x: [N,128] f32, w: [128,64] f32, h: [N,64] f32)
// Block = 256 threads = 4 rows x 64 out-dims. w fully staged in LDS (32 KB).
// ---------------------------------------------------------------------------
__global__ __launch_bounds__(256) void gc_gemm(const float* __restrict__ x,
                                               const float* __restrict__ w,
                                               float* __restrict__ h) {
    __shared__ float w_lds[IN_DIM * OUT_DIM];   // 32 KB
    __shared__ float x_lds[4 * IN_DIM];         // 2 KB

    const int tid = threadIdx.x;

    // Cooperative load of w: 8192 floats = 2048 float4; 8 per thread.
    const float4* w4 = reinterpret_cast<const float4*>(w);
    float4* wl4 = reinterpret_cast<float4*>(w_lds);
#pragma unroll
    for (int i = 0; i < 8; ++i) wl4[tid + i * 256] = w4[tid + i * 256];

    // Cooperative load of 4 x-rows: 512 floats = 128 float4 (threads 0..127).
    const int row0 = blockIdx.x * 4;  // N_NODES % 4 == 0, always in bounds
    if (tid < 128) {
        const float4* x4 = reinterpret_cast<const float4*>(x + (size_t)row0 * IN_DIM);
        reinterpret_cast<float4*>(x_lds)[tid] = x4[tid];
    }
    __syncthreads();

    const int r = tid >> 6;   // 0..3
    const int d = tid & 63;   // 0..63

    float acc = 0.0f;
#pragma unroll 8
    for (int k = 0; k < IN_DIM; ++k) {
        // x_lds read is a 64-lane broadcast (free); w_lds read is 2-way bank
        // aliased across 64 lanes (free on CDNA4).
        acc = fmaf(x_lds[r * IN_DIM + k], w_lds[k * OUT_DIM + d], acc);
    }
    h[(size_t)(row0 + r) * OUT_DIM + d] = acc;
}

// ---------------------------------------------------------------------------
// Kernel 2: scatter-add.  One thread per (edge, out-dim).
// out[dst[e]][d] += weight[e] * h[src[e]][d]
// 64-lane groups read/atomic contiguous 256 B slices -> coalesced.
// ---------------------------------------------------------------------------
__global__ __launch_bounds__(256) void gc_scatter(const float* __restrict__ h,
                                                  const int* __restrict__ esrc,
                                                  const int* __restrict__ edst,
                                                  const float* __restrict__ ew,
                                                  float* __restrict__ out) {
    const long long idx = (long long)blockIdx.x * 256 + threadIdx.x;
    const int e = (int)(idx >> 6);
    const int d = (int)(idx & 63);
    if (e >= N_EDGES) return;

    const int s = esrc[e];
    const int t = edst[e];
    const float v = ew[e] * h[(size_t)s * OUT_DIM + d];
    atomicAdd(&out[(size_t)t * OUT_DIM + d], v);
}

// ---------------------------------------------------------------------------
// Kernel 3: in-place ReLU on out (vectorized float4).
// ---------------------------------------------------------------------------
__global__ __launch_bounds__(256) void gc_relu(float* __restrict__ out) {
    const int i = blockIdx.x * 256 + threadIdx.x;
    const int n4 = N_NODES * OUT_DIM / 4;  // 800000
    if (i < n4) {
        float4* o4 = reinterpret_cast<float4*>(out);
        float4 v = o4[i];
        v.x = fmaxf(v.x, 0.0f);
        v.y = fmaxf(v.y, 0.0f);
        v.z = fmaxf(v.z, 0.0f);
        v.w = fmaxf(v.w, 0.0f);
        o4[i] = v;
    }
}

extern "C" void kernel_launch(void* const* d_in, const int* in_sizes, int n_in,
                              void* d_out, int out_size, void* d_ws, size_t ws_size,
                              hipStream_t stream) {
    const float* x    = (const float*)d_in[0];
    const int*   esrc = (const int*)d_in[1];
    const int*   edst = (const int*)d_in[2];
    const float* ew   = (const float*)d_in[3];
    const float* w    = (const float*)d_in[4];
    float* out = (float*)d_out;
    float* h   = (float*)d_ws;   // 12.8 MB scratch for projected features

    // Zero the accumulation target (harness poisons d_out with 0xAA).
    hipMemsetAsync(d_out, 0, (size_t)N_NODES * OUT_DIM * sizeof(float), stream);

    // h = x @ w
    gc_gemm<<<N_NODES / 4, 256, 0, stream>>>(x, w, h);

    // out[dst] += weight * h[src]
    const long long total = (long long)N_EDGES * OUT_DIM;
    const int nblk = (int)((total + 255) / 256);  // 200000
    gc_scatter<<<nblk, 256, 0, stream>>>(h, esrc, edst, ew, out);

    // out = relu(out)
    gc_relu<<<(N_NODES * OUT_DIM / 4 + 255) / 256, 256, 0, stream>>>(out);
}

// Round 2
// 273.545 us; speedup vs baseline: 1.1128x; 1.1128x over previous
//
#include <hip/hip_runtime.h>

#define N_NODES 50000
#define N_EDGES 800000
#define IN_DIM 128
#define OUT_DIM 64
#define ROWS 64   // rows per block in gemm

// ---------------------------------------------------------------------------
// Kernel 1: h = x @ w   (x: [N,128] f32, w: [128,64] f32, h: [N,64] f32)
// 256 threads = 16 dim-groups (tx) x 16 row-groups (ty).
// Each thread: 4 rows (ty + 16*i) x 4 dims (tx*4..tx*4+3), float4 accumulators.
// LDS: w [128][64] = 32 KB, x [64][128] = 32 KB with chunk-XOR swizzle so the
// 4 distinct row-addresses of one ds_read_b128 phase hit distinct bank slots.
// ---------------------------------------------------------------------------
__global__ __launch_bounds__(256, 2) void gc_gemm(const float* __restrict__ x,
                                                  const float* __restrict__ w,
                                                  float* __restrict__ h) {
    __shared__ float w_lds[IN_DIM * OUT_DIM];   // 32 KB
    __shared__ float x_lds[ROWS * IN_DIM];      // 32 KB (swizzled)

    const int tid = threadIdx.x;
    const int row0 = blockIdx.x * ROWS;

    // Stage w: 8192 floats = 2048 float4, 8 per thread, coalesced.
    const float4* w4 = reinterpret_cast<const float4*>(w);
    float4* wl4 = reinterpret_cast<float4*>(w_lds);
#pragma unroll
    for (int i = 0; i < 8; ++i) wl4[tid + i * 256] = w4[tid + i * 256];

    // Stage x tile: 64 rows x 32 float4 each, chunk index XOR-swizzled by row.
    const float4* x4 = reinterpret_cast<const float4*>(x);
    float4* xl4 = reinterpret_cast<float4*>(x_lds);
#pragma unroll
    for (int i = 0; i < 8; ++i) {
        const int idx = tid + i * 256;   // float4 index within tile
        const int r = idx >> 5;          // 32 float4 per row
        const int kc = idx & 31;
        const int g = row0 + r;
        float4 v = make_float4(0.f, 0.f, 0.f, 0.f);
        if (g < N_NODES) v = x4[(size_t)g * 32 + kc];
        xl4[r * 32 + (kc ^ (r & 3))] = v;
    }
    __syncthreads();

    const int tx = tid & 15;   // dim group: dims tx*4 .. tx*4+3
    const int ty = tid >> 4;   // row group: rows ty + 16*i
    const int sw = ty & 3;     // row swizzle key (same for all 4 of this thread's rows)

    float4 acc[4];
#pragma unroll
    for (int i = 0; i < 4; ++i) acc[i] = make_float4(0.f, 0.f, 0.f, 0.f);

    for (int kc = 0; kc < 32; ++kc) {
        float4 xv[4], wv[4];
#pragma unroll
        for (int i = 0; i < 4; ++i)
            xv[i] = xl4[(ty + 16 * i) * 32 + (kc ^ sw)];
#pragma unroll
        for (int j = 0; j < 4; ++j)
            wv[j] = wl4[(kc * 4 + j) * 16 + tx];
#pragma unroll
        for (int i = 0; i < 4; ++i) {
            acc[i].x = fmaf(xv[i].x, wv[0].x, acc[i].x);
            acc[i].y = fmaf(xv[i].x, wv[0].y, acc[i].y);
            acc[i].z = fmaf(xv[i].x, wv[0].z, acc[i].z);
            acc[i].w = fmaf(xv[i].x, wv[0].w, acc[i].w);
            acc[i].x = fmaf(xv[i].y, wv[1].x, acc[i].x);
            acc[i].y = fmaf(xv[i].y, wv[1].y, acc[i].y);
            acc[i].z = fmaf(xv[i].y, wv[1].z, acc[i].z);
            acc[i].w = fmaf(xv[i].y, wv[1].w, acc[i].w);
            acc[i].x = fmaf(xv[i].z, wv[2].x, acc[i].x);
            acc[i].y = fmaf(xv[i].z, wv[2].y, acc[i].y);
            acc[i].z = fmaf(xv[i].z, wv[2].z, acc[i].z);
            acc[i].w = fmaf(xv[i].z, wv[2].w, acc[i].w);
            acc[i].x = fmaf(xv[i].w, wv[3].x, acc[i].x);
            acc[i].y = fmaf(xv[i].w, wv[3].y, acc[i].y);
            acc[i].z = fmaf(xv[i].w, wv[3].z, acc[i].z);
            acc[i].w = fmaf(xv[i].w, wv[3].w, acc[i].w);
        }
    }

    float4* h4 = reinterpret_cast<float4*>(h);
#pragma unroll
    for (int i = 0; i < 4; ++i) {
        const int r = row0 + ty + 16 * i;
        if (r < N_NODES) h4[(size_t)r * 16 + tx] = acc[i];
    }
}

// ---------------------------------------------------------------------------
// Kernel 2: scatter-add.  One 64-lane wave per edge (grid exact: 200000*4=800000).
// out[dst[e]][d] += weight[e] * h[src[e]][d]
// e is wave-uniform -> readfirstlane so index/weight loads become scalar loads.
// ---------------------------------------------------------------------------
__global__ __launch_bounds__(256) void gc_scatter(const float* __restrict__ h,
                                                  const int* __restrict__ esrc,
                                                  const int* __restrict__ edst,
                                                  const float* __restrict__ ew,
                                                  float* __restrict__ out) {
    const int e = __builtin_amdgcn_readfirstlane(blockIdx.x * 4 + (threadIdx.x >> 6));
    const int d = threadIdx.x & 63;

    const int s = esrc[e];
    const int t = edst[e];
    const float v = ew[e] * h[(size_t)s * OUT_DIM + d];
    atomicAdd(&out[(size_t)t * OUT_DIM + d], v);
}

// ---------------------------------------------------------------------------
// Kernel 3: in-place ReLU on out (vectorized float4).
// ---------------------------------------------------------------------------
__global__ __launch_bounds__(256) void gc_relu(float* __restrict__ out) {
    const int i = blockIdx.x * 256 + threadIdx.x;
    const int n4 = N_NODES * OUT_DIM / 4;  // 800000
    if (i < n4) {
        float4* o4 = reinterpret_cast<float4*>(out);
        float4 v = o4[i];
        v.x = fmaxf(v.x, 0.0f);
        v.y = fmaxf(v.y, 0.0f);
        v.z = fmaxf(v.z, 0.0f);
        v.w = fmaxf(v.w, 0.0f);
        o4[i] = v;
    }
}

extern "C" void kernel_launch(void* const* d_in, const int* in_sizes, int n_in,
                              void* d_out, int out_size, void* d_ws, size_t ws_size,
                              hipStream_t stream) {
    const float* x    = (const float*)d_in[0];
    const int*   esrc = (const int*)d_in[1];
    const int*   edst = (const int*)d_in[2];
    const float* ew   = (const float*)d_in[3];
    const float* w    = (const float*)d_in[4];
    float* out = (float*)d_out;
    float* h   = (float*)d_ws;   // 12.8 MB scratch for projected features

    // Zero the accumulation target (harness poisons d_out with 0xAA).
    hipMemsetAsync(d_out, 0, (size_t)N_NODES * OUT_DIM * sizeof(float), stream);

    // h = x @ w
    gc_gemm<<<(N_NODES + ROWS - 1) / ROWS, 256, 0, stream>>>(x, w, h);

    // out[dst] += weight * h[src]
    gc_scatter<<<N_EDGES / 4, 256, 0, stream>>>(h, esrc, edst, ew, out);

    // out = relu(out)
    gc_relu<<<(N_NODES * OUT_DIM / 4 + 255) / 256, 256, 0, stream>>>(out);
}